// Round 1
// baseline (1237.903 us; speedup 1.0000x reference)
//
#include <hip/hip_runtime.h>
#include <hip/hip_bf16.h>
#include <math.h>

// Problem constants
#define NNODES 50000
#define NEDGES 800000
#define HID    128

// ---------------------------------------------------------------------------
// K1: node GEMM.  Hab[n][c] for c<128 = (h@Wa)[n][c] + b1[c];  c>=128 = (h@Wb)[n][c-128]
// SGEMM skeleton: 128-node tile x 128-channel tile, 8x8 micro, K=128 in BK=32 stages.
// grid = (ceil(N/128), 2), block = 256.  by selects Wa (0) or Wb (1).
// ---------------------------------------------------------------------------
__global__ __launch_bounds__(256) void k_gemm_node(
    const float* __restrict__ h, const float* __restrict__ W1,
    const float* __restrict__ b1, float* __restrict__ Hab)
{
    __shared__ float at[32][132];   // A transposed: at[k][node]
    __shared__ float bt[32][128];   // B: bt[k][c]

    const int tid = threadIdx.x;
    const int tx  = tid & 15;       // channel group: c = tx*8 .. tx*8+7
    const int ty  = tid >> 4;       // node group:    n = ty*8 .. ty*8+7
    const int nb  = blockIdx.x * 128;
    const int by  = blockIdx.y;     // 0 -> Wa, 1 -> Wb
    const float* W = W1 + by * 128 * 128;

    float acc[8][8];
#pragma unroll
    for (int j = 0; j < 8; ++j)
#pragma unroll
        for (int c = 0; c < 8; ++c) acc[j][c] = 0.0f;

    for (int ks = 0; ks < 128; ks += 32) {
        // stage A (clamped tail)
#pragma unroll
        for (int p = 0; p < 16; ++p) {
            int i  = (tid >> 5) + p * 8;
            int kk = tid & 31;
            int n  = nb + i;
            at[kk][i] = (n < NNODES) ? h[n * 128 + ks + kk] : 0.0f;
        }
        // stage B
#pragma unroll
        for (int p = 0; p < 16; ++p) {
            int kk = (tid >> 7) + p * 2;
            int c  = tid & 127;
            bt[kk][c] = W[(ks + kk) * 128 + c];
        }
        __syncthreads();
#pragma unroll
        for (int k = 0; k < 32; ++k) {
            float av[8], bv[8];
            *(float4*)&av[0] = *(const float4*)&at[k][ty * 8];
            *(float4*)&av[4] = *(const float4*)&at[k][ty * 8 + 4];
            *(float4*)&bv[0] = *(const float4*)&bt[k][tx * 8];
            *(float4*)&bv[4] = *(const float4*)&bt[k][tx * 8 + 4];
#pragma unroll
            for (int j = 0; j < 8; ++j)
#pragma unroll
                for (int c = 0; c < 8; ++c)
                    acc[j][c] = fmaf(av[j], bv[c], acc[j][c]);
        }
        __syncthreads();
    }

    // epilogue: +b1 for the Wa half, store
    float b1v[8];
    if (by == 0) {
        *(float4*)&b1v[0] = *(const float4*)&b1[tx * 8];
        *(float4*)&b1v[4] = *(const float4*)&b1[tx * 8 + 4];
    } else {
#pragma unroll
        for (int c = 0; c < 8; ++c) b1v[c] = 0.0f;
    }
#pragma unroll
    for (int j = 0; j < 8; ++j) {
        int n = nb + ty * 8 + j;
        if (n < NNODES) {
            float o[8];
#pragma unroll
            for (int c = 0; c < 8; ++c) o[c] = acc[j][c] + b1v[c];
            float* dst = Hab + (size_t)n * 256 + by * 128 + tx * 8;
            *(float4*)dst       = *(float4*)&o[0];
            *(float4*)(dst + 4) = *(float4*)&o[4];
        }
    }
}

// ---------------------------------------------------------------------------
// K2: edge GEMM + fused epilogue -> a[e]
// pre = edge_attr@Wc + Ha[row] + Hb[col]   (b1 already folded into Ha)
// a[e] = leaky_relu(elu(pre) . W2 + b2, 0.2)
// grid = 6250 (128 edges/block), block = 256.
// ---------------------------------------------------------------------------
__global__ __launch_bounds__(256) void k_gemm_edge(
    const float* __restrict__ ea, const int* __restrict__ eidx,
    const float* __restrict__ W1, const float* __restrict__ W2,
    const float* __restrict__ b2, const float* __restrict__ Hab,
    float* __restrict__ a_out)
{
    __shared__ float at[32][132];    // edge_attr transposed tile: at[k][e]
    __shared__ float bt[32][128];    // Wc tile: bt[k][c]
    __shared__ float red[128][17];   // per-edge partial reduction
    __shared__ float w2s[128];

    const int tid   = threadIdx.x;
    const int tx    = tid & 15;
    const int ty    = tid >> 4;
    const int ebase = blockIdx.x * 128;
    const float* Wc = W1 + 256 * 128;

    if (tid < 128) w2s[tid] = W2[tid];

    float acc[8][8];
#pragma unroll
    for (int j = 0; j < 8; ++j)
#pragma unroll
        for (int c = 0; c < 8; ++c) acc[j][c] = 0.0f;

    for (int ks = 0; ks < 128; ks += 32) {
#pragma unroll
        for (int p = 0; p < 16; ++p) {
            int i  = (tid >> 5) + p * 8;
            int kk = tid & 31;
            at[kk][i] = ea[(ebase + i) * 128 + ks + kk];
        }
#pragma unroll
        for (int p = 0; p < 16; ++p) {
            int kk = (tid >> 7) + p * 2;
            int c  = tid & 127;
            bt[kk][c] = Wc[(ks + kk) * 128 + c];
        }
        __syncthreads();
#pragma unroll
        for (int k = 0; k < 32; ++k) {
            float av[8], bv[8];
            *(float4*)&av[0] = *(const float4*)&at[k][ty * 8];
            *(float4*)&av[4] = *(const float4*)&at[k][ty * 8 + 4];
            *(float4*)&bv[0] = *(const float4*)&bt[k][tx * 8];
            *(float4*)&bv[4] = *(const float4*)&bt[k][tx * 8 + 4];
#pragma unroll
            for (int j = 0; j < 8; ++j)
#pragma unroll
                for (int c = 0; c < 8; ++c)
                    acc[j][c] = fmaf(av[j], bv[c], acc[j][c]);
        }
        __syncthreads();
    }

    // epilogue: gather Ha[row]/Hb[col], elu, dot with W2 (partial over 8 channels)
#pragma unroll
    for (int j = 0; j < 8; ++j) {
        int e  = ebase + ty * 8 + j;
        int r  = eidx[e];            // row
        int cj = eidx[NEDGES + e];   // col
        float ha[8], hb[8];
        const float* haRow = Hab + (size_t)r  * 256 + tx * 8;
        const float* hbRow = Hab + (size_t)cj * 256 + 128 + tx * 8;
        *(float4*)&ha[0] = *(const float4*)haRow;
        *(float4*)&ha[4] = *(const float4*)(haRow + 4);
        *(float4*)&hb[0] = *(const float4*)hbRow;
        *(float4*)&hb[4] = *(const float4*)(hbRow + 4);
        float s = 0.0f;
#pragma unroll
        for (int c = 0; c < 8; ++c) {
            float pre = acc[j][c] + ha[c] + hb[c];
            float el  = (pre > 0.0f) ? pre : expm1f(pre);
            s = fmaf(el, w2s[tx * 8 + c], s);
        }
        red[ty * 8 + j][tx] = s;
    }
    __syncthreads();
    if (tid < 128) {
        float s = 0.0f;
#pragma unroll
        for (int x = 0; x < 16; ++x) s += red[tid][x];
        s += b2[0];
        float aval = (s >= 0.0f) ? s : 0.2f * s;
        a_out[ebase + tid] = aval;
    }
}

// ---------------------------------------------------------------------------
// CSR build: histogram -> scan -> scatter
// ---------------------------------------------------------------------------
__global__ void k_hist(const int* __restrict__ eidx, int* __restrict__ hist)
{
    int e = blockIdx.x * 256 + threadIdx.x;
    if (e < NEDGES) atomicAdd(&hist[eidx[e]], 1);
}

__global__ void k_scan(const int* __restrict__ hist, int* __restrict__ offsets)
{
    __shared__ int sdata[1024];
    __shared__ int s_run;
    const int t = threadIdx.x;
    if (t == 0) s_run = 0;
    __syncthreads();
    for (int base = 0; base < NNODES; base += 1024) {
        int i = base + t;
        int v = (i < NNODES) ? hist[i] : 0;
        int run = s_run;
        sdata[t] = v;
        __syncthreads();
        for (int off = 1; off < 1024; off <<= 1) {
            int add = (t >= off) ? sdata[t - off] : 0;
            __syncthreads();
            sdata[t] += add;
            __syncthreads();
        }
        int incl = sdata[t];
        if (i < NNODES) offsets[i] = run + incl - v;   // exclusive
        __syncthreads();
        if (t == 1023) s_run = run + sdata[1023];
        __syncthreads();
    }
    if (t == 0) offsets[NNODES] = s_run;
}

__global__ void k_scatter(const int* __restrict__ eidx, const int* __restrict__ offsets,
                          int* __restrict__ cursor, int* __restrict__ sorted)
{
    int e = blockIdx.x * 256 + threadIdx.x;
    if (e < NEDGES) {
        int r   = eidx[e];
        int pos = offsets[r] + atomicAdd(&cursor[r], 1);
        sorted[pos] = e;
    }
}

// ---------------------------------------------------------------------------
// Softmax reductions over a[0..800000)
// ---------------------------------------------------------------------------
__global__ void k_rmax1(const float* __restrict__ a, float* __restrict__ partial)
{
    __shared__ float s[256];
    int tid = threadIdx.x;
    float m = -INFINITY;
    for (int i = blockIdx.x * 256 + tid; i < NEDGES; i += gridDim.x * 256)
        m = fmaxf(m, a[i]);
    s[tid] = m;
    __syncthreads();
    for (int off = 128; off > 0; off >>= 1) {
        if (tid < off) s[tid] = fmaxf(s[tid], s[tid + off]);
        __syncthreads();
    }
    if (tid == 0) partial[blockIdx.x] = s[0];
}

__global__ void k_rmax2(const float* __restrict__ partial, float* __restrict__ mz)
{
    __shared__ float s[256];
    int tid = threadIdx.x;
    float m = -INFINITY;
    for (int i = tid; i < 1024; i += 256) m = fmaxf(m, partial[i]);
    s[tid] = m;
    __syncthreads();
    for (int off = 128; off > 0; off >>= 1) {
        if (tid < off) s[tid] = fmaxf(s[tid], s[tid + off]);
        __syncthreads();
    }
    if (tid == 0) mz[0] = s[0];
}

__global__ void k_rsum1(const float* __restrict__ a, const float* __restrict__ mz,
                        float* __restrict__ partial)
{
    __shared__ float s[256];
    int tid = threadIdx.x;
    float M = mz[0];
    float acc = 0.0f;
    for (int i = blockIdx.x * 256 + tid; i < NEDGES; i += gridDim.x * 256)
        acc += expf(a[i] - M);
    s[tid] = acc;
    __syncthreads();
    for (int off = 128; off > 0; off >>= 1) {
        if (tid < off) s[tid] += s[tid + off];
        __syncthreads();
    }
    if (tid == 0) partial[blockIdx.x] = s[0];
}

__global__ void k_rsum2(const float* __restrict__ partial, float* __restrict__ mz)
{
    __shared__ float s[256];
    int tid = threadIdx.x;
    float acc = 0.0f;
    for (int i = tid; i < 1024; i += 256) acc += partial[i];
    s[tid] = acc;
    __syncthreads();
    for (int off = 128; off > 0; off >>= 1) {
        if (tid < off) s[tid] += s[tid + off];
        __syncthreads();
    }
    if (tid == 0) mz[1] = 1.0f / s[0];
}

// ---------------------------------------------------------------------------
// Aggregation: one wave per node, lanes cover 128 channels as float2.
// out[n][:] = sum over edges e with row[e]==n of alpha[e] * h[col[e]][:]
// grid = 12500, block = 256 (4 waves)
// ---------------------------------------------------------------------------
__global__ __launch_bounds__(256) void k_agg(
    const float* __restrict__ h, const int* __restrict__ eidx,
    const float* __restrict__ a, const int* __restrict__ sorted,
    const int* __restrict__ offsets, const float* __restrict__ mz,
    float* __restrict__ out)
{
    int node = blockIdx.x * 4 + (threadIdx.x >> 6);
    int lane = threadIdx.x & 63;
    if (node >= NNODES) return;
    float M = mz[0], invZ = mz[1];
    int s0 = offsets[node], s1 = offsets[node + 1];
    float2 acc = make_float2(0.0f, 0.0f);
    for (int i = s0; i < s1; ++i) {
        int e = sorted[i];
        float alpha = expf(a[e] - M) * invZ;
        int cj = eidx[NEDGES + e];
        float2 hj = *(const float2*)(h + (size_t)cj * 128 + lane * 2);
        acc.x = fmaf(alpha, hj.x, acc.x);
        acc.y = fmaf(alpha, hj.y, acc.y);
    }
    *(float2*)(out + (size_t)node * 128 + lane * 2) = acc;
}

// ---------------------------------------------------------------------------
extern "C" void kernel_launch(void* const* d_in, const int* in_sizes, int n_in,
                              void* d_out, int out_size, void* d_ws, size_t ws_size,
                              hipStream_t stream)
{
    const float* h    = (const float*)d_in[0];
    const int*   eidx = (const int*)d_in[1];   // [2][NEDGES], row = [0], col = [1]
    const float* ea   = (const float*)d_in[2];
    const float* W1   = (const float*)d_in[3];
    const float* b1   = (const float*)d_in[4];
    const float* W2   = (const float*)d_in[5];
    const float* b2   = (const float*)d_in[6];
    float* out = (float*)d_out;

    char* ws = (char*)d_ws;
    float* Hab     = (float*)(ws);                 // 50000*256*4 = 51,200,000
    float* a_arr   = (float*)(ws + 51200000);      // 3,200,000
    int*   sorted  = (int*)  (ws + 54400000);      // 3,200,000
    int*   offsets = (int*)  (ws + 57600000);      // 200,004 (padded region)
    int*   cursor  = (int*)  (ws + 57800192);      // 200,000 (doubles as histogram)
    float* pmax    = (float*)(ws + 58000192);      // 4096
    float* psum    = (float*)(ws + 58004288);      // 4096
    float* mz      = (float*)(ws + 58008384);      // 8

    // zero histogram
    hipMemsetAsync(cursor, 0, NNODES * sizeof(int), stream);

    // node GEMM (Ha|Hb)
    k_gemm_node<<<dim3((NNODES + 127) / 128, 2), 256, 0, stream>>>(h, W1, b1, Hab);

    // CSR build
    k_hist<<<(NEDGES + 255) / 256, 256, 0, stream>>>(eidx, cursor);
    k_scan<<<1, 1024, 0, stream>>>(cursor, offsets);
    hipMemsetAsync(cursor, 0, NNODES * sizeof(int), stream);
    k_scatter<<<(NEDGES + 255) / 256, 256, 0, stream>>>(eidx, offsets, cursor, sorted);

    // edge GEMM + epilogue -> a[e]
    k_gemm_edge<<<NEDGES / 128, 256, 0, stream>>>(ea, eidx, W1, W2, b2, Hab, a_arr);

    // softmax normalizers
    k_rmax1<<<1024, 256, 0, stream>>>(a_arr, pmax);
    k_rmax2<<<1, 256, 0, stream>>>(pmax, mz);
    k_rsum1<<<1024, 256, 0, stream>>>(a_arr, mz, psum);
    k_rsum2<<<1, 256, 0, stream>>>(psum, mz);

    // aggregate
    k_agg<<<(NNODES + 3) / 4, 256, 0, stream>>>(h, eidx, a_arr, sorted, offsets, mz, out);
}

// Round 3
// 1158.329 us; speedup vs baseline: 1.0687x; 1.0687x over previous
//
#include <hip/hip_runtime.h>
#include <hip/hip_bf16.h>
#include <math.h>

#define NNODES 50000
#define NEDGES 800000
#define HID    128
#define NB_SCAN 196   // ceil(50000/256)

typedef short bf16x8 __attribute__((ext_vector_type(8)));
typedef float f32x4  __attribute__((ext_vector_type(4)));

__device__ __forceinline__ unsigned short bf16_rn(float x) {
    union { float f; unsigned int u; } v; v.f = x;
    unsigned int r = v.u + 0x7fffu + ((v.u >> 16) & 1u);
    return (unsigned short)(r >> 16);
}
__device__ __forceinline__ float bf16_to_f(unsigned short u) {
    union { unsigned int u; float f; } v; v.u = ((unsigned int)u) << 16;
    return v.f;
}

// ---------------------------------------------------------------------------
// K0: transpose Wc (=W1[256:384]) into Wt[c][k] bf16 (32 KB, L2/L1 resident)
// ---------------------------------------------------------------------------
__global__ void k_prep(const float* __restrict__ W1, unsigned short* __restrict__ Wt)
{
    const float* Wc = W1 + 256 * 128;
    int t = threadIdx.x;
    for (int i = 0; i < 64; ++i) {
        int idx = t * 64 + i;
        int c = idx >> 7, k = idx & 127;
        Wt[c * 128 + k] = bf16_rn(Wc[k * 128 + c]);
    }
}

// ---------------------------------------------------------------------------
// K1: node GEMM -> Hab bf16.  c<128: (h@Wa)[n][c]+b1[c];  c>=128: (h@Wb)[n][c-128]
// ---------------------------------------------------------------------------
__global__ __launch_bounds__(256) void k_gemm_node(
    const float* __restrict__ h, const float* __restrict__ W1,
    const float* __restrict__ b1, unsigned short* __restrict__ Hab)
{
    __shared__ float at[32][132];
    __shared__ float bt[32][128];

    const int tid = threadIdx.x;
    const int tx  = tid & 15;
    const int ty  = tid >> 4;
    const int nb  = blockIdx.x * 128;
    const int by  = blockIdx.y;
    const float* W = W1 + by * 128 * 128;

    float acc[8][8];
#pragma unroll
    for (int j = 0; j < 8; ++j)
#pragma unroll
        for (int c = 0; c < 8; ++c) acc[j][c] = 0.0f;

    for (int ks = 0; ks < 128; ks += 32) {
#pragma unroll
        for (int p = 0; p < 16; ++p) {
            int i  = (tid >> 5) + p * 8;
            int kk = tid & 31;
            int n  = nb + i;
            at[kk][i] = (n < NNODES) ? h[n * 128 + ks + kk] : 0.0f;
        }
#pragma unroll
        for (int p = 0; p < 16; ++p) {
            int kk = (tid >> 7) + p * 2;
            int c  = tid & 127;
            bt[kk][c] = W[(ks + kk) * 128 + c];
        }
        __syncthreads();
#pragma unroll
        for (int k = 0; k < 32; ++k) {
            float av[8], bv[8];
            *(float4*)&av[0] = *(const float4*)&at[k][ty * 8];
            *(float4*)&av[4] = *(const float4*)&at[k][ty * 8 + 4];
            *(float4*)&bv[0] = *(const float4*)&bt[k][tx * 8];
            *(float4*)&bv[4] = *(const float4*)&bt[k][tx * 8 + 4];
#pragma unroll
            for (int j = 0; j < 8; ++j)
#pragma unroll
                for (int c = 0; c < 8; ++c)
                    acc[j][c] = fmaf(av[j], bv[c], acc[j][c]);
        }
        __syncthreads();
    }

    float b1v[8];
    if (by == 0) {
        *(float4*)&b1v[0] = *(const float4*)&b1[tx * 8];
        *(float4*)&b1v[4] = *(const float4*)&b1[tx * 8 + 4];
    } else {
#pragma unroll
        for (int c = 0; c < 8; ++c) b1v[c] = 0.0f;
    }
#pragma unroll
    for (int j = 0; j < 8; ++j) {
        int n = nb + ty * 8 + j;
        if (n < NNODES) {
            unsigned short o[8];
#pragma unroll
            for (int c = 0; c < 8; ++c) o[c] = bf16_rn(acc[j][c] + b1v[c]);
            unsigned short* dst = Hab + (size_t)n * 256 + by * 128 + tx * 8;
            *(int4*)dst = *(int4*)&o[0];
        }
    }
}

// ---------------------------------------------------------------------------
// K2: edge GEMM via bf16 MFMA, zero LDS.
// Block = 256 (4 waves), 128 edges/block. Each wave owns 32 edges x ALL 128
// channels (acc[2][8] tiles of 16x16x32) so the per-edge W2-dot is wave-local
// -> no cross-wave partial-sum race (R2 bug).
// A-frag: direct global fp32 loads of ea + cvt. B-frag: direct bf16 loads of Wt.
// C/D layout: col=lane&15 (channel), row=quad*4+reg (edge).
// ---------------------------------------------------------------------------
__global__ __launch_bounds__(256) void k_edge_mfma(
    const float* __restrict__ ea, const int* __restrict__ eidx,
    const unsigned short* __restrict__ Wt, const float* __restrict__ W2,
    const float* __restrict__ b2, const unsigned short* __restrict__ Hab,
    float* __restrict__ a_out)
{
    const int tid  = threadIdx.x;
    const int w    = tid >> 6;
    const int l    = tid & 63;
    const int quad = l >> 4;
    const int lm   = l & 15;
    const int wm   = w * 32;                 // 32 edges per wave
    const int ebase = blockIdx.x * 128;

    f32x4 acc[2][8] = {};

#pragma unroll
    for (int stage = 0; stage < 4; ++stage) {
        const int ks = stage * 32;
        bf16x8 bfrag[8];
#pragma unroll
        for (int nt = 0; nt < 8; ++nt) {
            const unsigned short* bp = Wt + (nt * 16 + lm) * 128 + ks + quad * 8;
            bfrag[nt] = *(const bf16x8*)bp;
        }
        bf16x8 afrag[2];
#pragma unroll
        for (int mt = 0; mt < 2; ++mt) {
            const float* ap = ea + (size_t)(ebase + wm + mt * 16 + lm) * 128 + ks + quad * 8;
            float4 x0 = *(const float4*)ap;
            float4 x1 = *(const float4*)(ap + 4);
            bf16x8 f;
            f[0] = (short)bf16_rn(x0.x); f[1] = (short)bf16_rn(x0.y);
            f[2] = (short)bf16_rn(x0.z); f[3] = (short)bf16_rn(x0.w);
            f[4] = (short)bf16_rn(x1.x); f[5] = (short)bf16_rn(x1.y);
            f[6] = (short)bf16_rn(x1.z); f[7] = (short)bf16_rn(x1.w);
            afrag[mt] = f;
        }
#pragma unroll
        for (int mt = 0; mt < 2; ++mt)
#pragma unroll
            for (int nt = 0; nt < 8; ++nt)
                acc[mt][nt] = __builtin_amdgcn_mfma_f32_16x16x32_bf16(
                    afrag[mt], bfrag[nt], acc[mt][nt], 0, 0, 0);
    }

    // epilogue: per edge, pre[c] = acc + Ha[row][c] + Hb[col][c]; elu; dot W2
    float w2v[8];
#pragma unroll
    for (int nt = 0; nt < 8; ++nt) w2v[nt] = W2[nt * 16 + lm];
    const float b2s = b2[0];

#pragma unroll
    for (int mt = 0; mt < 2; ++mt) {
        const int e4 = ebase + wm + mt * 16 + quad * 4;   // 4 edges of this quad
        float s0 = 0.f, s1 = 0.f, s2 = 0.f, s3 = 0.f;
#pragma unroll
        for (int r = 0; r < 4; ++r) {
            int e    = e4 + r;
            int row  = eidx[e];
            int colj = eidx[NEDGES + e];
            const unsigned short* hap = Hab + (size_t)row  * 256 + lm;
            const unsigned short* hbp = Hab + (size_t)colj * 256 + 128 + lm;
            float sr = 0.f;
#pragma unroll
            for (int nt = 0; nt < 8; ++nt) {
                float ha  = bf16_to_f(hap[nt * 16]);
                float hb  = bf16_to_f(hbp[nt * 16]);
                float pre = acc[mt][nt][r] + ha + hb;
                float el  = pre > 0.f ? pre : expm1f(pre);
                sr = fmaf(el, w2v[nt], sr);
            }
            if (r == 0) s0 = sr; else if (r == 1) s1 = sr; else if (r == 2) s2 = sr; else s3 = sr;
        }
        // reduce over the 16 lm-lanes of each quad group (xor masks 1,2,4,8)
#pragma unroll
        for (int m = 1; m < 16; m <<= 1) {
            s0 += __shfl_xor(s0, m, 64);
            s1 += __shfl_xor(s1, m, 64);
            s2 += __shfl_xor(s2, m, 64);
            s3 += __shfl_xor(s3, m, 64);
        }
        if (lm < 4) {
            float sum = (lm == 0) ? s0 : (lm == 1) ? s1 : (lm == 2) ? s2 : s3;
            sum += b2s;
            float av = sum >= 0.f ? sum : 0.2f * sum;
            a_out[e4 + lm] = av;
        }
    }
}

// ---------------------------------------------------------------------------
// CSR build: histogram -> 3-phase scan -> scatter (+ col stream)
// ---------------------------------------------------------------------------
__global__ void k_hist(const int* __restrict__ eidx, int* __restrict__ hist)
{
    int e = blockIdx.x * 256 + threadIdx.x;
    if (e < NEDGES) atomicAdd(&hist[eidx[e]], 1);
}

__global__ void k_scan_blk(const int* __restrict__ hist, int* __restrict__ offsets,
                           int* __restrict__ bsum)
{
    __shared__ int sd[256];
    int t = threadIdx.x, i = blockIdx.x * 256 + t;
    int v = (i < NNODES) ? hist[i] : 0;
    sd[t] = v; __syncthreads();
    for (int off = 1; off < 256; off <<= 1) {
        int add = (t >= off) ? sd[t - off] : 0;
        __syncthreads();
        sd[t] += add;
        __syncthreads();
    }
    if (i < NNODES) offsets[i] = sd[t] - v;
    if (t == 255) bsum[blockIdx.x] = sd[255];
}

__global__ void k_scan_top(const int* __restrict__ bsum, int* __restrict__ bpre,
                           int* __restrict__ offsets)
{
    __shared__ int sd[256];
    int t = threadIdx.x;
    int v = (t < NB_SCAN) ? bsum[t] : 0;
    sd[t] = v; __syncthreads();
    for (int off = 1; off < 256; off <<= 1) {
        int add = (t >= off) ? sd[t - off] : 0;
        __syncthreads();
        sd[t] += add;
        __syncthreads();
    }
    if (t < NB_SCAN) bpre[t] = sd[t] - v;
    if (t == 255) offsets[NNODES] = sd[255];
}

__global__ void k_scan_add(int* __restrict__ offsets, const int* __restrict__ bpre)
{
    int i = blockIdx.x * 256 + threadIdx.x;
    if (i < NNODES) offsets[i] += bpre[i >> 8];
}

__global__ void k_scatter(const int* __restrict__ eidx, const int* __restrict__ offsets,
                          int* __restrict__ cursor, int* __restrict__ sorted,
                          int* __restrict__ col_s)
{
    int e = blockIdx.x * 256 + threadIdx.x;
    if (e < NEDGES) {
        int r   = eidx[e];
        int pos = offsets[r] + atomicAdd(&cursor[r], 1);
        sorted[pos] = e;
        col_s[pos]  = eidx[NEDGES + e];
    }
}

// ---------------------------------------------------------------------------
// Softmax reductions
// ---------------------------------------------------------------------------
__global__ void k_rmax1(const float* __restrict__ a, float* __restrict__ partial)
{
    __shared__ float s[256];
    int tid = threadIdx.x;
    float m = -INFINITY;
    for (int i = blockIdx.x * 256 + tid; i < NEDGES; i += gridDim.x * 256)
        m = fmaxf(m, a[i]);
    s[tid] = m; __syncthreads();
    for (int off = 128; off > 0; off >>= 1) {
        if (tid < off) s[tid] = fmaxf(s[tid], s[tid + off]);
        __syncthreads();
    }
    if (tid == 0) partial[blockIdx.x] = s[0];
}

__global__ void k_rmax2(const float* __restrict__ partial, float* __restrict__ mz)
{
    __shared__ float s[256];
    int tid = threadIdx.x;
    float m = -INFINITY;
    for (int i = tid; i < 1024; i += 256) m = fmaxf(m, partial[i]);
    s[tid] = m; __syncthreads();
    for (int off = 128; off > 0; off >>= 1) {
        if (tid < off) s[tid] = fmaxf(s[tid], s[tid + off]);
        __syncthreads();
    }
    if (tid == 0) mz[0] = s[0];
}

__global__ void k_rsum1(const float* __restrict__ a, const float* __restrict__ mz,
                        float* __restrict__ partial)
{
    __shared__ float s[256];
    int tid = threadIdx.x;
    float M = mz[0];
    float acc = 0.0f;
    for (int i = blockIdx.x * 256 + tid; i < NEDGES; i += gridDim.x * 256)
        acc += expf(a[i] - M);
    s[tid] = acc; __syncthreads();
    for (int off = 128; off > 0; off >>= 1) {
        if (tid < off) s[tid] += s[tid + off];
        __syncthreads();
    }
    if (tid == 0) partial[blockIdx.x] = s[0];
}

__global__ void k_rsum2(const float* __restrict__ partial, float* __restrict__ mz)
{
    __shared__ float s[256];
    int tid = threadIdx.x;
    float acc = 0.0f;
    for (int i = tid; i < 1024; i += 256) acc += partial[i];
    s[tid] = acc; __syncthreads();
    for (int off = 128; off > 0; off >>= 1) {
        if (tid < off) s[tid] += s[tid + off];
        __syncthreads();
    }
    if (tid == 0) mz[1] = 1.0f / s[0];
}

// alpha_sorted in-place over `sorted`: reads sorted[i] (edge id), overwrites
// the slot with alpha as float.
__global__ void k_alpha(const float* __restrict__ a, const float* __restrict__ mz,
                        int* __restrict__ sorted_alpha)
{
    int i = blockIdx.x * 256 + threadIdx.x;
    if (i < NEDGES) {
        int e = sorted_alpha[i];
        float al = expf(a[e] - mz[0]) * mz[1];
        ((float*)sorted_alpha)[i] = al;
    }
}

// ---------------------------------------------------------------------------
// Aggregation: one wave per node; alpha/col are contiguous streams, only the
// h[col] read is a gather (inherent to the algorithm).
// ---------------------------------------------------------------------------
__global__ __launch_bounds__(256) void k_agg(
    const float* __restrict__ h, const float* __restrict__ alpha_s,
    const int* __restrict__ col_s, const int* __restrict__ offsets,
    float* __restrict__ out)
{
    int node = blockIdx.x * 4 + (threadIdx.x >> 6);
    int lane = threadIdx.x & 63;
    if (node >= NNODES) return;
    int s0 = offsets[node], s1 = offsets[node + 1];
    float2 acc = make_float2(0.0f, 0.0f);
    for (int i = s0; i < s1; ++i) {
        float al = alpha_s[i];
        int   cj = col_s[i];
        float2 hj = *(const float2*)(h + (size_t)cj * 128 + lane * 2);
        acc.x = fmaf(al, hj.x, acc.x);
        acc.y = fmaf(al, hj.y, acc.y);
    }
    *(float2*)(out + (size_t)node * 128 + lane * 2) = acc;
}

// ---------------------------------------------------------------------------
extern "C" void kernel_launch(void* const* d_in, const int* in_sizes, int n_in,
                              void* d_out, int out_size, void* d_ws, size_t ws_size,
                              hipStream_t stream)
{
    const float* h    = (const float*)d_in[0];
    const int*   eidx = (const int*)d_in[1];
    const float* ea   = (const float*)d_in[2];
    const float* W1   = (const float*)d_in[3];
    const float* b1   = (const float*)d_in[4];
    const float* W2   = (const float*)d_in[5];
    const float* b2   = (const float*)d_in[6];
    float* out = (float*)d_out;

    char* ws = (char*)d_ws;
    unsigned short* Hab = (unsigned short*)(ws);       // 25,600,000
    float* a_arr   = (float*)(ws + 25600000);          // 3,200,000
    int*   sorted  = (int*)  (ws + 28800000);          // 3,200,000 (becomes alpha_s)
    int*   col_s   = (int*)  (ws + 32000000);          // 3,200,000
    int*   offsets = (int*)  (ws + 35200000);          // 200,004 (padded)
    int*   cursor  = (int*)  (ws + 35400192);          // 200,000 (histogram too)
    float* pmax    = (float*)(ws + 35600384);          // 4096
    float* psum    = (float*)(ws + 35604480);          // 4096
    float* mz      = (float*)(ws + 35608576);          // 8
    int*   bsum    = (int*)  (ws + 35608640);          // 784 (pad 1024)
    int*   bpre    = (int*)  (ws + 35609664);          // 784 (pad 1024)
    unsigned short* Wt = (unsigned short*)(ws + 35610688); // 32,768

    hipMemsetAsync(cursor, 0, NNODES * sizeof(int), stream);

    k_prep<<<1, 256, 0, stream>>>(W1, Wt);
    k_gemm_node<<<dim3((NNODES + 127) / 128, 2), 256, 0, stream>>>(h, W1, b1, Hab);

    k_hist<<<(NEDGES + 255) / 256, 256, 0, stream>>>(eidx, cursor);
    k_scan_blk<<<NB_SCAN, 256, 0, stream>>>(cursor, offsets, bsum);
    k_scan_top<<<1, 256, 0, stream>>>(bsum, bpre, offsets);
    k_scan_add<<<NB_SCAN, 256, 0, stream>>>(offsets, bpre);
    hipMemsetAsync(cursor, 0, NNODES * sizeof(int), stream);
    k_scatter<<<(NEDGES + 255) / 256, 256, 0, stream>>>(eidx, offsets, cursor, sorted, col_s);

    k_edge_mfma<<<NEDGES / 128, 256, 0, stream>>>(ea, eidx, Wt, W2, b2, Hab, a_arr);

    k_rmax1<<<1024, 256, 0, stream>>>(a_arr, pmax);
    k_rmax2<<<1, 256, 0, stream>>>(pmax, mz);
    k_rsum1<<<1024, 256, 0, stream>>>(a_arr, mz, psum);
    k_rsum2<<<1, 256, 0, stream>>>(psum, mz);

    k_alpha<<<(NEDGES + 255) / 256, 256, 0, stream>>>(a_arr, mz, sorted);
    k_agg<<<(NNODES + 3) / 4, 256, 0, stream>>>(h, (const float*)sorted, col_s, offsets, out);
}